// Round 7
// baseline (268.580 us; speedup 1.0000x reference)
//
#include <hip/hip_runtime.h>

// out[i][d] = params[idx[i]] * xs[i][d];  N=4194304, D=8, V=1048576
//
// R7: bucket-swept gather. Two candidate ceilings fit all prior data:
//   (a) L2<->L3 fill motion ~6.4 TB/s: 272MB streams + 256MB gather fills
//       (4M random 4B gathers x 64B line, params thrashes out of 4MB L2)
//   (b) TCC request rate ~100G/s: 8.25M requests, irreducible.
// This kernel removes (a)'s gather-fill term without adding requests:
// each thread registers 8 rows' idx, then sweeps params in 4 x 1MB
// buckets. All blocks co-resident (grid = 8/CU, launch_bounds(256,8))
// -> every XCD gathers from the same 1MB window at the same time ->
// params stays L2-resident per phase -> fills 256MB -> ~32MB.
// idx read once (registers), xs/out unchanged, nt hints restored
// (R6 proved they cut FETCH 192->120MB and dur 103->85us).

typedef float f32x4 __attribute__((ext_vector_type(4)));

#define ROWS 8
#define NB   4
#define VTAB 1048576          // V (params table entries, fixed shape)
#define BSZ  (VTAB / NB)      // 262144 entries = 1 MB per bucket

__global__ __launch_bounds__(256, 8) void spvar_kernel(
    const f32x4* __restrict__ xs4,
    const int*   __restrict__ idx,
    const float* __restrict__ params,
    f32x4*       __restrict__ out4,
    int nrows, int stride)   // stride = gridDim.x * blockDim.x
{
    const int t = blockIdx.x * blockDim.x + threadIdx.x;

    // Stage 1: all idx into registers (coalesced, nt). OOB rows -> -1
    // (never matches any bucket; p stays 0 and row is never stored).
    int   ix[ROWS];
    float p[ROWS];
    #pragma unroll
    for (int u = 0; u < ROWS; ++u) {
        const int r = t + u * stride;
        ix[u] = (r < nrows) ? __builtin_nontemporal_load(idx + r) : -1;
        p[u]  = 0.0f;
    }

    // Stage 2: bucket sweep. All co-resident waves walk buckets in the
    // same order -> 1MB of params hot in each XCD L2 per phase.
    #pragma unroll
    for (int b = 0; b < NB; ++b) {
        const int lo = b * BSZ;
        #pragma unroll
        for (int u = 0; u < ROWS; ++u) {
            if ((unsigned)(ix[u] - lo) < (unsigned)BSZ)
                p[u] = params[ix[u]];           // plain policy: L2-allocating
        }
        __builtin_amdgcn_sched_barrier(0);      // pin bucket ordering
    }

    // Stage 3: stream xs -> scale -> stream out (nt, evict-first).
    #pragma unroll
    for (int u = 0; u < ROWS; ++u) {
        const int r = t + u * stride;
        if (r < nrows) {
            f32x4 a = __builtin_nontemporal_load(xs4 + 2 * r);
            f32x4 c = __builtin_nontemporal_load(xs4 + 2 * r + 1);
            a *= p[u];
            c *= p[u];
            __builtin_nontemporal_store(a, out4 + 2 * r);
            __builtin_nontemporal_store(c, out4 + 2 * r + 1);
        }
    }
}

extern "C" void kernel_launch(void* const* d_in, const int* in_sizes, int n_in,
                              void* d_out, int out_size, void* d_ws, size_t ws_size,
                              hipStream_t stream) {
    const float* xs     = (const float*)d_in[0];   // [N, 8] f32
    const int*   idx    = (const int*)d_in[1];     // [N] int32 (jax x64 off)
    const float* params = (const float*)d_in[2];   // [V, 1] f32

    const int nrows = out_size / 8;                // N (out_size is f32 ELEMENTS, D=8)
    const int block = 256;
    const int grid  = (nrows + block * ROWS - 1) / (block * ROWS);  // 2048 for N=4M
    const int stride = grid * block;               // = 8 blocks/CU, all co-resident

    spvar_kernel<<<grid, block, 0, stream>>>(
        (const f32x4*)xs, idx, params, (f32x4*)d_out, nrows, stride);
}